// Round 1
// baseline (4674.731 us; speedup 1.0000x reference)
//
#include <hip/hip_runtime.h>
#include <math.h>

#define BB 32      // batch
#define SS 64      // seq len
#define HH 256     // hidden
#define OO 32000   // vocab out

// ---------------------------------------------------------------------------
// Kernel 1: xp[t][b][g] = dot(emb[x[b][t]], W_ih[g,:]) + b_ih[g] + b_hh[g]
// Grid: 64 blocks (each 32 rows r = t*32+b), 256 threads (one per g).
// ---------------------------------------------------------------------------
__global__ __launch_bounds__(256) void xp_kernel(
    const int* __restrict__ x, const float* __restrict__ emb,
    const float* __restrict__ W_ih, const float* __restrict__ b_ih,
    const float* __restrict__ b_hh, float* __restrict__ xp)
{
    __shared__ float xe[32][HH];      // 32 KB
    __shared__ float wbuf[256][33];   // padded chunk of W_ih, ~33.8 KB

    const int g  = threadIdx.x;
    const int r0 = blockIdx.x * 32;

    // stage 32 embedding rows (coalesced per row)
    for (int rl = 0; rl < 32; ++rl) {
        int r = r0 + rl;
        int t = r >> 5, b = r & 31;
        int idx = x[b * SS + t];
        xe[rl][g] = emb[(size_t)idx * HH + g];
    }

    float acc[32];
#pragma unroll
    for (int rl = 0; rl < 32; ++rl) acc[rl] = 0.f;

    for (int c = 0; c < HH / 32; ++c) {
        __syncthreads();
        // stage W_ih[:, c*32 .. c*32+32) coalesced
        for (int it = 0; it < 32; ++it) {
            int e  = it * 256 + g;
            int gg = e >> 5, hh = e & 31;
            wbuf[gg][hh] = W_ih[(size_t)gg * HH + c * 32 + hh];
        }
        __syncthreads();
        for (int hh = 0; hh < 32; ++hh) {
            float wv = wbuf[g][hh];       // conflict-free (stride 33)
            int h = c * 32 + hh;
#pragma unroll
            for (int rl = 0; rl < 32; ++rl)
                acc[rl] = fmaf(wv, xe[rl][h], acc[rl]);  // xe: LDS broadcast
        }
    }

    float bias = b_ih[g] + b_hh[g];
    for (int rl = 0; rl < 32; ++rl)
        xp[(size_t)(r0 + rl) * HH + g] = acc[rl] + bias;
}

// ---------------------------------------------------------------------------
// Kernel 2: the serial recurrence. One block per batch element (32 blocks),
// 1024 threads: thread (g,q) accumulates quarter-dot over h in [64q,64q+64).
// W_hh slice in VGPRs, h + xp slice + partials in LDS. 4096 steps.
// Snapshots at k = 65*i -> hs_sel[i][b][:]; k=4095 -> h_final (d_out[0:8192]).
// ---------------------------------------------------------------------------
__global__ __launch_bounds__(1024) void rnn_kernel(
    const float* __restrict__ W_hh, const float* __restrict__ xp,
    float* __restrict__ hs_sel, float* __restrict__ out0)
{
    __shared__ float xp_lds[SS * HH];              // 64 KB
    __shared__ __align__(16) float h_lds[HH];      // 1 KB
    __shared__ float part[4 * HH];                 // 4 KB

    const int tid = threadIdx.x;
    const int b   = blockIdx.x;
    const int g   = tid & 255;
    const int q   = tid >> 8;

    // W_hh[g][q*64 + j] slice into registers (one-time, L1/L2 absorbs)
    float w[64];
#pragma unroll
    for (int j = 0; j < 64; ++j)
        w[j] = W_hh[(size_t)g * HH + q * 64 + j];

    // preload this block's xp slice: xp[t][b][:] -> xp_lds[t*HH+:]
    for (int tt = q; tt < SS; tt += 4)
        xp_lds[tt * HH + g] = xp[((size_t)tt * BB + b) * HH + g];

    if (tid < HH) h_lds[tid] = 0.f;
    __syncthreads();

    int next_snap = 0, i_snap = 0;
    for (int k = 0; k < SS * SS; ++k) {
        const int t = k & (SS - 1);

        float acc = 0.f;
        const float4* h4 = (const float4*)(h_lds + q * 64);
#pragma unroll
        for (int j4 = 0; j4 < 16; ++j4) {
            float4 hv = h4[j4];                    // uniform -> LDS broadcast
            acc = fmaf(w[4 * j4 + 0], hv.x, acc);
            acc = fmaf(w[4 * j4 + 1], hv.y, acc);
            acc = fmaf(w[4 * j4 + 2], hv.z, acc);
            acc = fmaf(w[4 * j4 + 3], hv.w, acc);
        }
        part[q * HH + g] = acc;
        __syncthreads();

        if (tid < HH) {
            float u = xp_lds[t * HH + tid] + part[tid] + part[HH + tid]
                    + part[2 * HH + tid] + part[3 * HH + tid];
            float hn = tanhf(u);
            h_lds[tid] = hn;
            if (k == next_snap)
                hs_sel[((size_t)i_snap * BB + b) * HH + tid] = hn;
            if (k == SS * SS - 1)
                out0[(size_t)b * HH + tid] = hn;   // h_final
        }
        if (k == next_snap) { next_snap += 65; ++i_snap; }  // uniform update
        __syncthreads();
    }
}

// ---------------------------------------------------------------------------
// Kernel 3: logits y[r][o] = dot(hrow[r], W_out[o,:]) + b_out[o],
// rows r = b*64 + i (matches out layout [B,S,O]), hrow[r] = hs_sel[i][b][:].
// Grid: (125 o-chunks, 64 row-groups), 256 threads (one o per thread).
// ---------------------------------------------------------------------------
__global__ __launch_bounds__(256) void proj_kernel(
    const float* __restrict__ hs_sel, const float* __restrict__ W_out,
    const float* __restrict__ b_out, float* __restrict__ out1)
{
    __shared__ float ht[32][HH];      // 32 KB
    __shared__ float wbuf[256][33];   // ~33.8 KB  -> 2 blocks/CU

    const int o_l = threadIdx.x;
    const int oc  = blockIdx.x;       // 0..124
    const int r0  = blockIdx.y * 32;  // row group
    const int o   = oc * 256 + o_l;

    for (int rl = 0; rl < 32; ++rl) {
        int r  = r0 + rl;
        int bb = r >> 6, ii = r & 63;
        ht[rl][o_l] = hs_sel[((size_t)ii * BB + bb) * HH + o_l];
    }

    float acc[32];
#pragma unroll
    for (int rl = 0; rl < 32; ++rl) acc[rl] = 0.f;

    for (int c = 0; c < HH / 32; ++c) {
        __syncthreads();
        for (int it = 0; it < 32; ++it) {
            int e  = it * 256 + o_l;
            int gg = e >> 5, hh = e & 31;
            wbuf[gg][hh] = W_out[(size_t)(oc * 256 + gg) * HH + c * 32 + hh];
        }
        __syncthreads();
        for (int hh = 0; hh < 32; ++hh) {
            float wv = wbuf[o_l][hh];
            int h = c * 32 + hh;
#pragma unroll
            for (int rl = 0; rl < 32; ++rl)
                acc[rl] = fmaf(wv, ht[rl][h], acc[rl]);
        }
    }

    float bo = b_out[o];
    for (int rl = 0; rl < 32; ++rl) {
        int r = r0 + rl;
        out1[(size_t)r * OO + o] = acc[rl] + bo;
    }
}

// ---------------------------------------------------------------------------
extern "C" void kernel_launch(void* const* d_in, const int* in_sizes, int n_in,
                              void* d_out, int out_size, void* d_ws, size_t ws_size,
                              hipStream_t stream)
{
    const int*   x     = (const int*)  d_in[0];
    const float* emb   = (const float*)d_in[1];
    const float* W_ih  = (const float*)d_in[2];
    const float* W_hh  = (const float*)d_in[3];
    const float* b_ih  = (const float*)d_in[4];
    const float* b_hh  = (const float*)d_in[5];
    const float* W_out = (const float*)d_in[6];
    const float* b_out = (const float*)d_in[7];

    float* out  = (float*)d_out;
    float* out0 = out;                     // h_final: [1,B,H] = 8192 floats
    float* out1 = out + (size_t)BB * HH;   // ys: [B,S,O]

    float* xp     = (float*)d_ws;                        // S*B*H = 2 MB
    float* hs_sel = xp + (size_t)SS * BB * HH;           // S*B*H = 2 MB

    xp_kernel<<<dim3(SS * BB / 32), dim3(256), 0, stream>>>(x, emb, W_ih, b_ih, b_hh, xp);
    rnn_kernel<<<dim3(BB), dim3(1024), 0, stream>>>(W_hh, xp, hs_sel, out0);
    proj_kernel<<<dim3(OO / 256, SS * BB / 32), dim3(256), 0, stream>>>(hs_sel, W_out, b_out, out1);
}

// Round 3
// 4595.901 us; speedup vs baseline: 1.0172x; 1.0172x over previous
//
#include <hip/hip_runtime.h>
#include <hip/hip_bf16.h>
#include <math.h>

#define BB 32      // batch
#define SS 64      // seq len
#define HH 256     // hidden
#define OO 32000   // vocab out

typedef float v2f __attribute__((ext_vector_type(2)));
using f32x4  = __attribute__((ext_vector_type(4))) float;
using bf16x8 = __attribute__((ext_vector_type(8))) short;

// ---------------------------------------------------------------------------
// Kernel 1: xp[t][b][g] = dot(emb[x[b][t]], W_ih[g,:]) + b_ih[g] + b_hh[g]
// ---------------------------------------------------------------------------
__global__ __launch_bounds__(256) void xp_kernel(
    const int* __restrict__ x, const float* __restrict__ emb,
    const float* __restrict__ W_ih, const float* __restrict__ b_ih,
    const float* __restrict__ b_hh, float* __restrict__ xp)
{
    __shared__ float xe[32][HH];      // 32 KB
    __shared__ float wbuf[256][33];   // padded chunk of W_ih

    const int g  = threadIdx.x;
    const int r0 = blockIdx.x * 32;

    for (int rl = 0; rl < 32; ++rl) {
        int r = r0 + rl;
        int t = r >> 5, b = r & 31;
        int idx = x[b * SS + t];
        xe[rl][g] = emb[(size_t)idx * HH + g];
    }

    float acc[32];
#pragma unroll
    for (int rl = 0; rl < 32; ++rl) acc[rl] = 0.f;

    for (int c = 0; c < HH / 32; ++c) {
        __syncthreads();
        for (int it = 0; it < 32; ++it) {
            int e  = it * 256 + g;
            int gg = e >> 5, hh = e & 31;
            wbuf[gg][hh] = W_ih[(size_t)gg * HH + c * 32 + hh];
        }
        __syncthreads();
        for (int hh = 0; hh < 32; ++hh) {
            float wv = wbuf[g][hh];
            int h = c * 32 + hh;
#pragma unroll
            for (int rl = 0; rl < 32; ++rl)
                acc[rl] = fmaf(wv, xe[rl][h], acc[rl]);
        }
    }

    float bias = b_ih[g] + b_hh[g];
    for (int rl = 0; rl < 32; ++rl)
        xp[(size_t)(r0 + rl) * HH + g] = acc[rl] + bias;
}

// ---------------------------------------------------------------------------
// Kernel 2: serial recurrence. 32 blocks (one per batch), 512 threads:
// thread (g = tid>>1, q = tid&1) computes half-dot over h[q*128..+128).
// Pair-reduce via shfl_xor(1). Double-buffered h in LDS -> ONE barrier/step.
// Fast tanh: tanh(u) = 1 - 2/(exp(2u)+1) via v_exp_f32 + v_rcp_f32.
// Snapshots at k = 65*i -> A_bf16[b*64+i][:]; k=4095 -> h_final (out0).
// ---------------------------------------------------------------------------
__global__ __launch_bounds__(512) void rnn_kernel(
    const float* __restrict__ W_hh, const float* __restrict__ xp,
    __hip_bfloat16* __restrict__ A, float* __restrict__ out0)
{
    __shared__ float xp_lds[SS * HH];               // 64 KB
    __shared__ __align__(16) float h_lds[2][HH];    // 2 KB double buffer

    const int tid = threadIdx.x;
    const int b   = blockIdx.x;
    const int g   = tid >> 1;
    const int q   = tid & 1;

    // W_hh[g][q*128 + 2j .. +2] as packed float2 registers (128 VGPRs)
    v2f w2[64];
    {
        const float* wrow = W_hh + (size_t)g * HH + q * 128;
#pragma unroll
        for (int j = 0; j < 64; ++j)
            w2[j] = *(const v2f*)(wrow + 2 * j);
    }

    for (int idx = tid; idx < SS * HH; idx += 512) {
        int t = idx >> 8, gg = idx & 255;
        xp_lds[idx] = xp[((size_t)t * BB + b) * HH + gg];
    }
    if (tid < HH) h_lds[0][tid] = 0.f;
    __syncthreads();

    int next_snap = 0, i_snap = 0;
    for (int k = 0; k < SS * SS; ++k) {
        const float4* h4 = (const float4*)(&h_lds[k & 1][q * 128]);
        v2f acc2 = {0.f, 0.f};
#pragma unroll
        for (int j = 0; j < 32; ++j) {
            float4 hv = h4[j];               // 2-way LDS alias (free)
            v2f ha = {hv.x, hv.y};
            v2f hb = {hv.z, hv.w};
            acc2 = __builtin_elementwise_fma(w2[2 * j],     ha, acc2);
            acc2 = __builtin_elementwise_fma(w2[2 * j + 1], hb, acc2);
        }
        float acc = acc2.x + acc2.y;
        acc += __shfl_xor(acc, 1);           // partner lane has other half

        float u  = xp_lds[(k & 63) * HH + g] + acc;
        float e  = __expf(2.f * u);
        float hn = 1.f - 2.f * __builtin_amdgcn_rcpf(e + 1.f);

        if (q == 0) {
            h_lds[(k + 1) & 1][g] = hn;
            if (k == next_snap)
                A[((size_t)((b << 6) + i_snap)) * HH + g] = __float2bfloat16(hn);
            if (k == SS * SS - 1)
                out0[(size_t)b * HH + g] = hn;
        }
        if (k == next_snap) { next_snap += 65; ++i_snap; }
        __syncthreads();                     // new h visible for next step
    }
}

// ---------------------------------------------------------------------------
// Kernel 3a: convert W_out (fp32) -> bf16, 8 elems/thread
// ---------------------------------------------------------------------------
__global__ __launch_bounds__(256) void cvt_kernel(
    const float* __restrict__ W, __hip_bfloat16* __restrict__ Wb)
{
    int i = (blockIdx.x * 256 + threadIdx.x) * 8;
    float4 a = *(const float4*)(W + i);
    float4 c = *(const float4*)(W + i + 4);
    union { __hip_bfloat16 h[8]; uint4 u; } r;
    r.h[0] = __float2bfloat16(a.x); r.h[1] = __float2bfloat16(a.y);
    r.h[2] = __float2bfloat16(a.z); r.h[3] = __float2bfloat16(a.w);
    r.h[4] = __float2bfloat16(c.x); r.h[5] = __float2bfloat16(c.y);
    r.h[6] = __float2bfloat16(c.z); r.h[7] = __float2bfloat16(c.w);
    *(uint4*)(Wb + i) = r.u;
}

// ---------------------------------------------------------------------------
// Kernel 3b: logits = A[2048x256] @ Wb[32000x256]^T + b_out, bf16 MFMA.
// 128x128 tile, BK=128 (2 K-steps), 4 waves in 2x2, 16x16x32 MFMA.
// Reg-staged LDS with +8 bf16 pad.
// ---------------------------------------------------------------------------
__global__ __launch_bounds__(256) void proj_kernel(
    const __hip_bfloat16* __restrict__ A,   // [2048][256]
    const __hip_bfloat16* __restrict__ Wb,  // [32000][256]
    const float* __restrict__ b_out, float* __restrict__ out1)
{
    constexpr int PAD = 8;
    __shared__ __hip_bfloat16 As[128][128 + PAD];
    __shared__ __hip_bfloat16 Bs[128][128 + PAD];

    const int t    = threadIdx.x;
    const int n0   = blockIdx.x * 128;
    const int m0   = blockIdx.y * 128;
    const int wid  = t >> 6, lane = t & 63;
    const int wm   = wid >> 1, wn = wid & 1;
    const int l15  = lane & 15, lhi = lane >> 4;

    f32x4 acc[4][4] = {};

    const int row_l = t >> 4;          // 0..15
    const int colb  = (t & 15) * 8;    // element offset (16B chunks)

    for (int kt = 0; kt < 2; ++kt) {
        __syncthreads();
        for (int p = 0; p < 8; ++p) {
            int row = p * 16 + row_l;
            uint4 va = *(const uint4*)(A  + ((size_t)(m0 + row) * HH + kt * 128 + colb));
            uint4 vb = *(const uint4*)(Wb + ((size_t)(n0 + row) * HH + kt * 128 + colb));
            *(uint4*)(&As[row][colb]) = va;
            *(uint4*)(&Bs[row][colb]) = vb;
        }
        __syncthreads();
#pragma unroll
        for (int kk = 0; kk < 4; ++kk) {
            bf16x8 af[4], bfr[4];
#pragma unroll
            for (int m = 0; m < 4; ++m)
                af[m] = *(const bf16x8*)(&As[wm * 64 + m * 16 + l15][kk * 32 + lhi * 8]);
#pragma unroll
            for (int n = 0; n < 4; ++n)
                bfr[n] = *(const bf16x8*)(&Bs[wn * 64 + n * 16 + l15][kk * 32 + lhi * 8]);
#pragma unroll
            for (int m = 0; m < 4; ++m)
#pragma unroll
                for (int n = 0; n < 4; ++n)
                    acc[m][n] = __builtin_amdgcn_mfma_f32_16x16x32_bf16(
                        af[m], bfr[n], acc[m][n], 0, 0, 0);
        }
    }

    // epilogue: C/D layout col=lane&15, row=(lane>>4)*4+reg
#pragma unroll
    for (int n = 0; n < 4; ++n) {
        int col = n0 + wn * 64 + n * 16 + l15;
        float bo = b_out[col];
#pragma unroll
        for (int m = 0; m < 4; ++m) {
            int row = m0 + wm * 64 + m * 16 + lhi * 4;
#pragma unroll
            for (int j = 0; j < 4; ++j)
                out1[(size_t)(row + j) * OO + col] = acc[m][n][j] + bo;
        }
    }
}

// ---------------------------------------------------------------------------
extern "C" void kernel_launch(void* const* d_in, const int* in_sizes, int n_in,
                              void* d_out, int out_size, void* d_ws, size_t ws_size,
                              hipStream_t stream)
{
    const int*   x     = (const int*)  d_in[0];
    const float* emb   = (const float*)d_in[1];
    const float* W_ih  = (const float*)d_in[2];
    const float* W_hh  = (const float*)d_in[3];
    const float* b_ih  = (const float*)d_in[4];
    const float* b_hh  = (const float*)d_in[5];
    const float* W_out = (const float*)d_in[6];
    const float* b_out = (const float*)d_in[7];

    float* out  = (float*)d_out;
    float* out0 = out;                     // h_final: [1,B,H]
    float* out1 = out + (size_t)BB * HH;   // ys: [B,S,O]

    float*          xp = (float*)d_ws;                          // 2 MB
    __hip_bfloat16* A  = (__hip_bfloat16*)(xp + (size_t)SS * BB * HH);   // 1 MB
    __hip_bfloat16* Wb = A + (size_t)BB * SS * HH;                        // 16.4 MB

    xp_kernel<<<dim3(SS * BB / 32), dim3(256), 0, stream>>>(x, emb, W_ih, b_ih, b_hh, xp);
    cvt_kernel<<<dim3(OO * HH / (256 * 8)), dim3(256), 0, stream>>>(W_out, Wb);
    rnn_kernel<<<dim3(BB), dim3(512), 0, stream>>>(W_hh, xp, A, out0);
    proj_kernel<<<dim3(OO / 128, (BB * SS) / 128), dim3(256), 0, stream>>>(A, Wb, b_out, out1);
}

// Round 5
// 3337.532 us; speedup vs baseline: 1.4007x; 1.3770x over previous
//
#include <hip/hip_runtime.h>
#include <hip/hip_bf16.h>
#include <math.h>

#define BB 32      // batch
#define SS 64      // seq len
#define HH 256     // hidden
#define OO 32000   // vocab out

using f4     = __attribute__((ext_vector_type(4))) float;
using f32x4  = __attribute__((ext_vector_type(4))) float;
using bf16x8 = __attribute__((ext_vector_type(8))) short;

// ---------------------------------------------------------------------------
// Kernel 1: xp[t][b][g] = dot(emb[x[b][t]], W_ih[g,:]) + b_ih[g] + b_hh[g]
// ---------------------------------------------------------------------------
__global__ __launch_bounds__(256) void xp_kernel(
    const int* __restrict__ x, const float* __restrict__ emb,
    const float* __restrict__ W_ih, const float* __restrict__ b_ih,
    const float* __restrict__ b_hh, float* __restrict__ xp)
{
    __shared__ float xe[32][HH];      // 32 KB
    __shared__ float wbuf[256][33];   // padded chunk of W_ih

    const int g  = threadIdx.x;
    const int r0 = blockIdx.x * 32;

    for (int rl = 0; rl < 32; ++rl) {
        int r = r0 + rl;
        int t = r >> 5, b = r & 31;
        int idx = x[b * SS + t];
        xe[rl][g] = emb[(size_t)idx * HH + g];
    }

    float acc[32];
#pragma unroll
    for (int rl = 0; rl < 32; ++rl) acc[rl] = 0.f;

    for (int c = 0; c < HH / 32; ++c) {
        __syncthreads();
        for (int it = 0; it < 32; ++it) {
            int e  = it * 256 + g;
            int gg = e >> 5, hh = e & 31;
            wbuf[gg][hh] = W_ih[(size_t)gg * HH + c * 32 + hh];
        }
        __syncthreads();
        for (int hh = 0; hh < 32; ++hh) {
            float wv = wbuf[g][hh];
            int h = c * 32 + hh;
#pragma unroll
            for (int rl = 0; rl < 32; ++rl)
                acc[rl] = fmaf(wv, xe[rl][h], acc[rl]);
        }
    }

    float bias = b_ih[g] + b_hh[g];
    for (int rl = 0; rl < 32; ++rl)
        xp[(size_t)(r0 + rl) * HH + g] = acc[rl] + bias;
}

// ---------------------------------------------------------------------------
// Kernel 2: serial recurrence. 32 blocks (one per batch), 512 threads.
//   wid = tid>>6, lane = tid&63, q = lane>>5 (half-wave), g = wid*32+(lane&31)
// Thread (g,q) accumulates the half-dot over h[q*128 .. q*128+128).
//   - W_hh slice (128 floats) pinned in VGPRs via inline-asm keep-alive.
//   - h double-buffered in LDS, two 144-float regions (bank-disjoint for the
//     two uniform half-wave broadcast addresses) -> 0 conflicts, 1 barrier/step.
//   - pair reduce: __shfl_xor(acc, 32) (partner is lane^32, same wave).
// Snapshots at k = 65*i -> A_bf16[b*64+i][:]; k=4095 -> h_final (out0).
// ---------------------------------------------------------------------------
__global__ __launch_bounds__(512, 2) void rnn_kernel(
    const float* __restrict__ W_hh, const float* __restrict__ xp,
    __hip_bfloat16* __restrict__ A, float* __restrict__ out0)
{
    __shared__ float xp_lds[SS * HH];                 // 64 KB
    __shared__ __align__(16) float hbuf[2][288];      // 2 regions of 144 floats

    const int tid  = threadIdx.x;
    const int b    = blockIdx.x;
    const int lane = tid & 63;
    const int wid  = tid >> 6;
    const int q    = lane >> 5;          // 0 or 1, uniform per half-wave
    const int g    = wid * 32 + (lane & 31);

    // --- W_hh[g][q*128 .. +128) into 32 float4 registers, pinned ---
    f4 w4[32];
    {
        const float* wrow = W_hh + (size_t)g * HH + q * 128;
#pragma unroll
        for (int j = 0; j < 32; ++j) {
            w4[j] = *(const f4*)(wrow + 4 * j);
            asm volatile("" : "+v"(w4[j]));   // force VGPR residency (no remat/spill)
        }
    }

    // stage xp slice for this batch: xp_lds[t*HH+g] = xp[t][b][g]
    for (int idx = tid; idx < SS * HH; idx += 512) {
        int t = idx >> 8, gg = idx & 255;
        xp_lds[idx] = xp[((size_t)t * BB + b) * HH + gg];
    }
    for (int idx = tid; idx < 288; idx += 512) hbuf[0][idx] = 0.f;
    __syncthreads();

    int next_snap = 0, i_snap = 0;
    for (int k = 0; k < SS * SS; ++k) {
        // uniform per half-wave: region q of current buffer
        const f4* h4 = (const f4*)(&hbuf[k & 1][q * 144]);
        float acc = 0.f;
#pragma unroll
        for (int j = 0; j < 32; ++j) {
            f4 hv = h4[j];                    // broadcast, bank-disjoint vs other half
            acc = fmaf(w4[j][0], hv[0], acc);
            acc = fmaf(w4[j][1], hv[1], acc);
            acc = fmaf(w4[j][2], hv[2], acc);
            acc = fmaf(w4[j][3], hv[3], acc);
        }
        acc += __shfl_xor(acc, 32);           // combine the two half-dots

        float u  = xp_lds[(k & 63) * HH + g] + acc;
        float e  = __expf(2.f * u);
        float hn = 1.f - 2.f * __builtin_amdgcn_rcpf(e + 1.f);

        if (q == 0) {
            // h'[g] -> region (g>>7), offset (g&127), next buffer
            hbuf[(k + 1) & 1][(g >> 7) * 144 + (g & 127)] = hn;
            if (k == next_snap)
                A[((size_t)((b << 6) + i_snap)) * HH + g] = __float2bfloat16(hn);
            if (k == SS * SS - 1)
                out0[(size_t)b * HH + g] = hn;
        }
        if (k == next_snap) { next_snap += 65; ++i_snap; }
        __syncthreads();                      // new h visible for next step
    }
}

// ---------------------------------------------------------------------------
// Kernel 3a: convert W_out (fp32) -> bf16, 8 elems/thread
// ---------------------------------------------------------------------------
__global__ __launch_bounds__(256) void cvt_kernel(
    const float* __restrict__ W, __hip_bfloat16* __restrict__ Wb)
{
    int i = (blockIdx.x * 256 + threadIdx.x) * 8;
    float4 a = *(const float4*)(W + i);
    float4 c = *(const float4*)(W + i + 4);
    union { __hip_bfloat16 h[8]; uint4 u; } r;
    r.h[0] = __float2bfloat16(a.x); r.h[1] = __float2bfloat16(a.y);
    r.h[2] = __float2bfloat16(a.z); r.h[3] = __float2bfloat16(a.w);
    r.h[4] = __float2bfloat16(c.x); r.h[5] = __float2bfloat16(c.y);
    r.h[6] = __float2bfloat16(c.z); r.h[7] = __float2bfloat16(c.w);
    *(uint4*)(Wb + i) = r.u;
}

// ---------------------------------------------------------------------------
// Kernel 3b: logits = A[2048x256] @ Wb[32000x256]^T + b_out, bf16 MFMA.
// 128x128 tile, BK=128 (2 K-steps), 4 waves in 2x2, 16x16x32 MFMA.
// ---------------------------------------------------------------------------
__global__ __launch_bounds__(256) void proj_kernel(
    const __hip_bfloat16* __restrict__ A,   // [2048][256]
    const __hip_bfloat16* __restrict__ Wb,  // [32000][256]
    const float* __restrict__ b_out, float* __restrict__ out1)
{
    constexpr int PAD = 8;
    __shared__ __hip_bfloat16 As[128][128 + PAD];
    __shared__ __hip_bfloat16 Bs[128][128 + PAD];

    const int t    = threadIdx.x;
    const int n0   = blockIdx.x * 128;
    const int m0   = blockIdx.y * 128;
    const int wid  = t >> 6, lane = t & 63;
    const int wm   = wid >> 1, wn = wid & 1;
    const int l15  = lane & 15, lhi = lane >> 4;

    f32x4 acc[4][4] = {};

    const int row_l = t >> 4;          // 0..15
    const int colb  = (t & 15) * 8;    // element offset (16B chunks)

    for (int kt = 0; kt < 2; ++kt) {
        __syncthreads();
        for (int p = 0; p < 8; ++p) {
            int row = p * 16 + row_l;
            uint4 va = *(const uint4*)(A  + ((size_t)(m0 + row) * HH + kt * 128 + colb));
            uint4 vb = *(const uint4*)(Wb + ((size_t)(n0 + row) * HH + kt * 128 + colb));
            *(uint4*)(&As[row][colb]) = va;
            *(uint4*)(&Bs[row][colb]) = vb;
        }
        __syncthreads();
#pragma unroll
        for (int kk = 0; kk < 4; ++kk) {
            bf16x8 af[4], bfr[4];
#pragma unroll
            for (int m = 0; m < 4; ++m)
                af[m] = *(const bf16x8*)(&As[wm * 64 + m * 16 + l15][kk * 32 + lhi * 8]);
#pragma unroll
            for (int n = 0; n < 4; ++n)
                bfr[n] = *(const bf16x8*)(&Bs[wn * 64 + n * 16 + l15][kk * 32 + lhi * 8]);
#pragma unroll
            for (int m = 0; m < 4; ++m)
#pragma unroll
                for (int n = 0; n < 4; ++n)
                    acc[m][n] = __builtin_amdgcn_mfma_f32_16x16x32_bf16(
                        af[m], bfr[n], acc[m][n], 0, 0, 0);
        }
    }

    // epilogue: C/D layout col=lane&15, row=(lane>>4)*4+reg
#pragma unroll
    for (int n = 0; n < 4; ++n) {
        int col = n0 + wn * 64 + n * 16 + l15;
        float bo = b_out[col];
#pragma unroll
        for (int m = 0; m < 4; ++m) {
            int row = m0 + wm * 64 + m * 16 + lhi * 4;
#pragma unroll
            for (int j = 0; j < 4; ++j)
                out1[(size_t)(row + j) * OO + col] = acc[m][n][j] + bo;
        }
    }
}

// ---------------------------------------------------------------------------
extern "C" void kernel_launch(void* const* d_in, const int* in_sizes, int n_in,
                              void* d_out, int out_size, void* d_ws, size_t ws_size,
                              hipStream_t stream)
{
    const int*   x     = (const int*)  d_in[0];
    const float* emb   = (const float*)d_in[1];
    const float* W_ih  = (const float*)d_in[2];
    const float* W_hh  = (const float*)d_in[3];
    const float* b_ih  = (const float*)d_in[4];
    const float* b_hh  = (const float*)d_in[5];
    const float* W_out = (const float*)d_in[6];
    const float* b_out = (const float*)d_in[7];

    float* out  = (float*)d_out;
    float* out0 = out;                     // h_final: [1,B,H]
    float* out1 = out + (size_t)BB * HH;   // ys: [B,S,O]

    float*          xp = (float*)d_ws;                                   // 2 MB
    __hip_bfloat16* A  = (__hip_bfloat16*)(xp + (size_t)SS * BB * HH);   // 1 MB
    __hip_bfloat16* Wb = A + (size_t)BB * SS * HH;                       // 16.4 MB

    xp_kernel<<<dim3(SS * BB / 32), dim3(256), 0, stream>>>(x, emb, W_ih, b_ih, b_hh, xp);
    cvt_kernel<<<dim3(OO * HH / (256 * 8)), dim3(256), 0, stream>>>(W_out, Wb);
    rnn_kernel<<<dim3(BB), dim3(512), 0, stream>>>(W_hh, xp, A, out0);
    proj_kernel<<<dim3(OO / 128, (BB * SS) / 128), dim3(256), 0, stream>>>(A, Wb, b_out, out1);
}

// Round 6
// 2420.036 us; speedup vs baseline: 1.9317x; 1.3791x over previous
//
#include <hip/hip_runtime.h>
#include <hip/hip_bf16.h>
#include <math.h>

#define BB 32      // batch
#define SS 64      // seq len
#define HH 256     // hidden
#define OO 32000   // vocab out

using f32x4  = __attribute__((ext_vector_type(4))) float;
using bf16x8 = __attribute__((ext_vector_type(8))) short;
typedef _Float16 h2f __attribute__((ext_vector_type(2)));

// ---------------------------------------------------------------------------
// Kernel 1: xp[t][b][g] = dot(emb[x[b][t]], W_ih[g,:]) + b_ih[g] + b_hh[g]
// ---------------------------------------------------------------------------
__global__ __launch_bounds__(256) void xp_kernel(
    const int* __restrict__ x, const float* __restrict__ emb,
    const float* __restrict__ W_ih, const float* __restrict__ b_ih,
    const float* __restrict__ b_hh, float* __restrict__ xp)
{
    __shared__ float xe[32][HH];      // 32 KB
    __shared__ float wbuf[256][33];   // padded chunk of W_ih

    const int g  = threadIdx.x;
    const int r0 = blockIdx.x * 32;

    for (int rl = 0; rl < 32; ++rl) {
        int r = r0 + rl;
        int t = r >> 5, b = r & 31;
        int idx = x[b * SS + t];
        xe[rl][g] = emb[(size_t)idx * HH + g];
    }

    float acc[32];
#pragma unroll
    for (int rl = 0; rl < 32; ++rl) acc[rl] = 0.f;

    for (int c = 0; c < HH / 32; ++c) {
        __syncthreads();
        for (int it = 0; it < 32; ++it) {
            int e  = it * 256 + g;
            int gg = e >> 5, hh = e & 31;
            wbuf[gg][hh] = W_ih[(size_t)gg * HH + c * 32 + hh];
        }
        __syncthreads();
        for (int hh = 0; hh < 32; ++hh) {
            float wv = wbuf[g][hh];
            int h = c * 32 + hh;
#pragma unroll
            for (int rl = 0; rl < 32; ++rl)
                acc[rl] = fmaf(wv, xe[rl][h], acc[rl]);
        }
    }

    float bias = b_ih[g] + b_hh[g];
    for (int rl = 0; rl < 32; ++rl)
        xp[(size_t)(r0 + rl) * HH + g] = acc[rl] + bias;
}

// ---------------------------------------------------------------------------
// Kernel 2: serial recurrence, fp16 dot2 with fp32 accumulate.
// 32 blocks (one per batch), 512 threads.
//   wid = tid>>6, lane = tid&63, q = lane>>5 (half-wave), g = wid*32+(lane&31)
// Thread (g,q): half-dot over h[q*128 .. +128) via 64 v_dot2_f32_f16.
//   - W_hh slice as 64 packed-half dwords in VGPRs (pinned per-dword).
//   - h as half2 in LDS, double-buffered; region stride 164 dwords ->
//     the two half-wave broadcast addresses are bank-disjoint.
//   - pair reduce: __shfl_xor(acc, 32); ONE barrier per step.
// Snapshots at k = 65*i -> A_bf16[b*64+i][:]; k=4095 -> h_final (out0).
// ---------------------------------------------------------------------------
__global__ __launch_bounds__(512, 2) void rnn_kernel(
    const float* __restrict__ W_hh, const float* __restrict__ xp,
    __hip_bfloat16* __restrict__ A, float* __restrict__ out0)
{
    __shared__ float xp_lds[SS * HH];                 // 64 KB
    __shared__ __align__(16) unsigned int hbuf[2][2][164];  // h as half2, padded regions

    const int tid  = threadIdx.x;
    const int b    = blockIdx.x;
    const int lane = tid & 63;
    const int wid  = tid >> 6;
    const int q    = lane >> 5;          // 0 or 1, uniform per half-wave
    const int g    = wid * 32 + (lane & 31);

    // --- W_hh[g][q*128 .. +128) as 64 packed half2 dwords, pinned ---
    unsigned int w_u[64];
    {
        const float* wrow = W_hh + (size_t)g * HH + q * 128;
#pragma unroll
        for (int j = 0; j < 32; ++j) {
            float4 f = *(const float4*)(wrow + 4 * j);
            h2f a = {(_Float16)f.x, (_Float16)f.y};
            h2f c = {(_Float16)f.z, (_Float16)f.w};
            w_u[2 * j]     = __builtin_bit_cast(unsigned int, a);
            w_u[2 * j + 1] = __builtin_bit_cast(unsigned int, c);
            asm volatile("" : "+v"(w_u[2 * j]));       // 4B pin: well-formed
            asm volatile("" : "+v"(w_u[2 * j + 1]));
        }
    }

    // stage xp slice for this batch: xp_lds[t*HH+g] = xp[t][b][g]
    for (int idx = tid; idx < SS * HH; idx += 512) {
        int t = idx >> 8, gg = idx & 255;
        xp_lds[idx] = xp[((size_t)t * BB + b) * HH + gg];
    }
    for (int idx = tid; idx < 2 * 2 * 164; idx += 512)
        ((unsigned int*)hbuf)[idx] = 0u;               // h0 = 0 (and pads)
    __syncthreads();

    int next_snap = 0, i_snap = 0;
    for (int k = 0; k < SS * SS; ++k) {
        // uniform per half-wave: 16 x 16B broadcast reads of region q
        const uint4* h4 = (const uint4*)(&hbuf[k & 1][q][0]);
        float acc = 0.f;
#pragma unroll
        for (int j = 0; j < 16; ++j) {
            uint4 hv = h4[j];
#if __has_builtin(__builtin_amdgcn_fdot2)
            acc = __builtin_amdgcn_fdot2(__builtin_bit_cast(h2f, w_u[4*j+0]),
                                         __builtin_bit_cast(h2f, hv.x), acc, false);
            acc = __builtin_amdgcn_fdot2(__builtin_bit_cast(h2f, w_u[4*j+1]),
                                         __builtin_bit_cast(h2f, hv.y), acc, false);
            acc = __builtin_amdgcn_fdot2(__builtin_bit_cast(h2f, w_u[4*j+2]),
                                         __builtin_bit_cast(h2f, hv.z), acc, false);
            acc = __builtin_amdgcn_fdot2(__builtin_bit_cast(h2f, w_u[4*j+3]),
                                         __builtin_bit_cast(h2f, hv.w), acc, false);
#else
            {
                h2f wv0 = __builtin_bit_cast(h2f, w_u[4*j+0]), hv0 = __builtin_bit_cast(h2f, hv.x);
                h2f wv1 = __builtin_bit_cast(h2f, w_u[4*j+1]), hv1 = __builtin_bit_cast(h2f, hv.y);
                h2f wv2 = __builtin_bit_cast(h2f, w_u[4*j+2]), hv2 = __builtin_bit_cast(h2f, hv.z);
                h2f wv3 = __builtin_bit_cast(h2f, w_u[4*j+3]), hv3 = __builtin_bit_cast(h2f, hv.w);
                acc = fmaf((float)wv0[0], (float)hv0[0], acc); acc = fmaf((float)wv0[1], (float)hv0[1], acc);
                acc = fmaf((float)wv1[0], (float)hv1[0], acc); acc = fmaf((float)wv1[1], (float)hv1[1], acc);
                acc = fmaf((float)wv2[0], (float)hv2[0], acc); acc = fmaf((float)wv2[1], (float)hv2[1], acc);
                acc = fmaf((float)wv3[0], (float)hv3[0], acc); acc = fmaf((float)wv3[1], (float)hv3[1], acc);
            }
#endif
        }
        acc += __shfl_xor(acc, 32);           // combine the two half-dots

        float u  = xp_lds[(k & 63) * HH + g] + acc;
        float e  = __expf(2.f * u);
        float hn = 1.f - 2.f * __builtin_amdgcn_rcpf(e + 1.f);

        if (q == 0) {
            // write h'[g] as fp16 into region (g>>7), slot (g&127), next buffer
            _Float16* dst = (_Float16*)(&hbuf[(k + 1) & 1][g >> 7][0]);
            dst[g & 127] = (_Float16)hn;
            if (k == next_snap)
                A[((size_t)((b << 6) + i_snap)) * HH + g] = __float2bfloat16(hn);
            if (k == SS * SS - 1)
                out0[(size_t)b * HH + g] = hn;
        }
        if (k == next_snap) { next_snap += 65; ++i_snap; }
        __syncthreads();                      // new h visible for next step
    }
}

// ---------------------------------------------------------------------------
// Kernel 3a: convert W_out (fp32) -> bf16, 8 elems/thread
// ---------------------------------------------------------------------------
__global__ __launch_bounds__(256) void cvt_kernel(
    const float* __restrict__ W, __hip_bfloat16* __restrict__ Wb)
{
    int i = (blockIdx.x * 256 + threadIdx.x) * 8;
    float4 a = *(const float4*)(W + i);
    float4 c = *(const float4*)(W + i + 4);
    union { __hip_bfloat16 h[8]; uint4 u; } r;
    r.h[0] = __float2bfloat16(a.x); r.h[1] = __float2bfloat16(a.y);
    r.h[2] = __float2bfloat16(a.z); r.h[3] = __float2bfloat16(a.w);
    r.h[4] = __float2bfloat16(c.x); r.h[5] = __float2bfloat16(c.y);
    r.h[6] = __float2bfloat16(c.z); r.h[7] = __float2bfloat16(c.w);
    *(uint4*)(Wb + i) = r.u;
}

// ---------------------------------------------------------------------------
// Kernel 3b: logits = A[2048x256] @ Wb[32000x256]^T + b_out, bf16 MFMA.
// 128x128 tile, BK=128 (2 K-steps), 4 waves in 2x2, 16x16x32 MFMA.
// ---------------------------------------------------------------------------
__global__ __launch_bounds__(256) void proj_kernel(
    const __hip_bfloat16* __restrict__ A,   // [2048][256]
    const __hip_bfloat16* __restrict__ Wb,  // [32000][256]
    const float* __restrict__ b_out, float* __restrict__ out1)
{
    constexpr int PAD = 8;
    __shared__ __hip_bfloat16 As[128][128 + PAD];
    __shared__ __hip_bfloat16 Bs[128][128 + PAD];

    const int t    = threadIdx.x;
    const int n0   = blockIdx.x * 128;
    const int m0   = blockIdx.y * 128;
    const int wid  = t >> 6, lane = t & 63;
    const int wm   = wid >> 1, wn = wid & 1;
    const int l15  = lane & 15, lhi = lane >> 4;

    f32x4 acc[4][4] = {};

    const int row_l = t >> 4;          // 0..15
    const int colb  = (t & 15) * 8;    // element offset (16B chunks)

    for (int kt = 0; kt < 2; ++kt) {
        __syncthreads();
        for (int p = 0; p < 8; ++p) {
            int row = p * 16 + row_l;
            uint4 va = *(const uint4*)(A  + ((size_t)(m0 + row) * HH + kt * 128 + colb));
            uint4 vb = *(const uint4*)(Wb + ((size_t)(n0 + row) * HH + kt * 128 + colb));
            *(uint4*)(&As[row][colb]) = va;
            *(uint4*)(&Bs[row][colb]) = vb;
        }
        __syncthreads();
#pragma unroll
        for (int kk = 0; kk < 4; ++kk) {
            bf16x8 af[4], bfr[4];
#pragma unroll
            for (int m = 0; m < 4; ++m)
                af[m] = *(const bf16x8*)(&As[wm * 64 + m * 16 + l15][kk * 32 + lhi * 8]);
#pragma unroll
            for (int n = 0; n < 4; ++n)
                bfr[n] = *(const bf16x8*)(&Bs[wn * 64 + n * 16 + l15][kk * 32 + lhi * 8]);
#pragma unroll
            for (int m = 0; m < 4; ++m)
#pragma unroll
                for (int n = 0; n < 4; ++n)
                    acc[m][n] = __builtin_amdgcn_mfma_f32_16x16x32_bf16(
                        af[m], bfr[n], acc[m][n], 0, 0, 0);
        }
    }

    // epilogue: C/D layout col=lane&15, row=(lane>>4)*4+reg
#pragma unroll
    for (int n = 0; n < 4; ++n) {
        int col = n0 + wn * 64 + n * 16 + l15;
        float bo = b_out[col];
#pragma unroll
        for (int m = 0; m < 4; ++m) {
            int row = m0 + wm * 64 + m * 16 + lhi * 4;
#pragma unroll
            for (int j = 0; j < 4; ++j)
                out1[(size_t)(row + j) * OO + col] = acc[m][n][j] + bo;
        }
    }
}

// ---------------------------------------------------------------------------
extern "C" void kernel_launch(void* const* d_in, const int* in_sizes, int n_in,
                              void* d_out, int out_size, void* d_ws, size_t ws_size,
                              hipStream_t stream)
{
    const int*   x     = (const int*)  d_in[0];
    const float* emb   = (const float*)d_in[1];
    const float* W_ih  = (const float*)d_in[2];
    const float* W_hh  = (const float*)d_in[3];
    const float* b_ih  = (const float*)d_in[4];
    const float* b_hh  = (const float*)d_in[5];
    const float* W_out = (const float*)d_in[6];
    const float* b_out = (const float*)d_in[7];

    float* out  = (float*)d_out;
    float* out0 = out;                     // h_final: [1,B,H]
    float* out1 = out + (size_t)BB * HH;   // ys: [B,S,O]

    float*          xp = (float*)d_ws;                                   // 2 MB
    __hip_bfloat16* A  = (__hip_bfloat16*)(xp + (size_t)SS * BB * HH);   // 1 MB
    __hip_bfloat16* Wb = A + (size_t)BB * SS * HH;                       // 16.4 MB

    xp_kernel<<<dim3(SS * BB / 32), dim3(256), 0, stream>>>(x, emb, W_ih, b_ih, b_hh, xp);
    cvt_kernel<<<dim3(OO * HH / (256 * 8)), dim3(256), 0, stream>>>(W_out, Wb);
    rnn_kernel<<<dim3(BB), dim3(512), 0, stream>>>(W_hh, xp, A, out0);
    proj_kernel<<<dim3(OO / 128, (BB * SS) / 128), dim3(256), 0, stream>>>(A, Wb, b_out, out1);
}